// Round 1
// 118.638 us; speedup vs baseline: 1.0100x; 1.0100x over previous
//
#include <hip/hip_runtime.h>

typedef float v2f __attribute__((ext_vector_type(2)));

static constexpr int N_AGENTS = 64;   // = wave size; one lane per agent/edge
static constexpr int H_DIM    = 8;
static constexpr int ROWS     = 4;    // rows per wave-iteration (2x v2f packed)

__device__ __forceinline__ float fast_exp2(float v) {
#if __has_builtin(__builtin_amdgcn_exp2f)
    return __builtin_amdgcn_exp2f(v);   // v_exp_f32
#else
    return exp2f(v);
#endif
}

__device__ __forceinline__ float fast_rcp(float v) {
#if __has_builtin(__builtin_amdgcn_rcpf)
    return __builtin_amdgcn_rcpf(v);    // v_rcp_f32
#else
    return 1.0f / v;
#endif
}

__device__ __forceinline__ v2f fma2(v2f a, v2f b, v2f c) {
    return __builtin_elementwise_fma(a, b, c);   // -> v_pk_fma_f32
}
__device__ __forceinline__ v2f splat(float s) { return (v2f){s, s}; }
__device__ __forceinline__ v2f exp2_2(v2f a) {
    v2f z; z.x = fast_exp2(a.x); z.y = fast_exp2(a.y); return z;
}
__device__ __forceinline__ v2f rcp2(v2f a) {
    v2f r; r.x = fast_rcp(a.x); r.y = fast_rcp(a.y); return r;
}

// tanh folded into consumer:
//   tanh(a) = 1 - 2*r,  r = rcp(exp2(K*a) + 1),  K = 2*log2(e) pre-folded into
//   first-layer weights; consumer acc += tanh*w  ==>  acc0 = base + sum(w),
//   acc = fma(r, -2w, acc).
//
// NEW this round: 4-way batched reciprocal. rcp is a quarter-rate
// transcendental; for each group of 4 activations we compute one
// q = rcp(z0*z1*z2*z3) (2 scalar rcp for the v2f pair) and recover the four
// 1/zi with 9 packed muls. Cuts per-element trans ops 32 -> 20.
// Overflow-safe: z_i <= ~1e9 for these weight/input magnitudes, so the
// 4-product stays far below f32 max.

__global__ __launch_bounds__(256) void networked_ode_kernel(
    const float* __restrict__ x,    // [B, N] f32
    const float* __restrict__ W1,   // [N, H]
    const float* __restrict__ b1,   // [N, H]
    const float* __restrict__ W2,   // [N, H]
    const float* __restrict__ b2,   // [N]
    const float* __restrict__ Wc1,  // [2, H]
    const float* __restrict__ bc1,  // [H]
    const float* __restrict__ Wc2,  // [H]
    const float* __restrict__ bc2,  // [1]
    const int* __restrict__ send_idx,  // [N]
    const int* __restrict__ recv_idx,  // [N]
    float* __restrict__ out,        // [B, N] f32
    int B)
{
    const int lane           = threadIdx.x & 63;
    const int wave_in_block  = threadIdx.x >> 6;
    const int waves_per_blk  = blockDim.x >> 6;
    const int gwave          = blockIdx.x * waves_per_blk + wave_in_block;
    const int total_waves    = gridDim.x * waves_per_blk;

    const float K = 2.8853900817779268f;  // 2*log2(e)

    // ---- per-lane (agent) intrinsic weights, prescaled + consumer-folded
    float w1s[H_DIM], b1s[H_DIM], m2w2[H_DIM];
    float acc0 = b2[lane];
#pragma unroll
    for (int h = 0; h < H_DIM; ++h) {
        w1s[h] = W1[lane * H_DIM + h] * K;
        b1s[h] = b1[lane * H_DIM + h] * K;
        const float w2v = W2[lane * H_DIM + h];
        m2w2[h] = -2.0f * w2v;
        acc0 += w2v;
    }

    // ---- wave-uniform coupling weights (compiler -> SGPRs)
    float wcss[H_DIM], wcrs[H_DIM], bc1s[H_DIM], m2wc2[H_DIM];
    float c0 = bc2[0];
#pragma unroll
    for (int h = 0; h < H_DIM; ++h) {
        wcss[h] = Wc1[h] * K;             // Wc1[0][h] (x_send)
        wcrs[h] = Wc1[H_DIM + h] * K;     // Wc1[1][h] (x_recv)
        bc1s[h] = bc1[h] * K;
        const float wc2v = Wc2[h];
        m2wc2[h] = -2.0f * wc2v;
        c0 += wc2v;
    }

    // ---- edge endpoints for edge e = lane
    const int sidx = send_idx[lane];
    const int ridx = recv_idx[lane];

    // ring topology in practice: send == identity permutation. Detect it
    // wave-uniformly so we can skip 2 of the 4 shuffles per row (generic
    // fallback keeps correctness for any permutation).
    const bool send_is_id = (__ballot(sidx == lane) == ~0ull);

    // ---- scatter-add becomes gather via inverse permutation (computed once)
    __shared__ int inv_r_s[256], inv_s_s[256];
    const int base = wave_in_block * 64;
    inv_r_s[base + ridx] = lane;
    inv_s_s[base + sidx] = lane;
    __syncthreads();
    const int inv_r = inv_r_s[base + lane];  // edge whose recv == my agent
    const int inv_s = inv_s_s[base + lane];  // edge whose send == my agent

    // ---- grid-stride, 4 rows per iteration (2x v2f) for ILP + packed math
    for (int row0 = gwave * ROWS; row0 < B; row0 += total_waves * ROWS) {
        float xv[ROWS], xs[ROWS], xr[ROWS];
#pragma unroll
        for (int k = 0; k < ROWS; ++k) {
            const int row = row0 + k;
            xv[k] = (row < B) ? x[(size_t)row * N_AGENTS + lane] : 0.0f;
        }
#pragma unroll
        for (int k = 0; k < ROWS; ++k) xr[k] = __shfl(xv[k], ridx, 64);
        if (send_is_id) {
#pragma unroll
            for (int k = 0; k < ROWS; ++k) xs[k] = xv[k];
        } else {
#pragma unroll
            for (int k = 0; k < ROWS; ++k) xs[k] = __shfl(xv[k], sidx, 64);
        }

        v2f XV[2] = {{xv[0], xv[1]}, {xv[2], xv[3]}};
        v2f XS[2] = {{xs[0], xs[1]}, {xs[2], xs[3]}};
        v2f XR[2] = {{xr[0], xr[1]}, {xr[2], xr[3]}};
        v2f C[2]  = {splat(c0), splat(c0)};
        v2f A[2]  = {splat(acc0), splat(acc0)};
        const v2f one = splat(1.0f);

        // coupling MLP (edge = lane): 2 groups of 4 h, batched reciprocal
#pragma unroll
        for (int g = 0; g < 2; ++g) {
#pragma unroll
            for (int p = 0; p < 2; ++p) {
                v2f z0, z1, z2, z3;
                {
                    v2f a = fma2(XR[p], splat(wcrs[4*g+0]), splat(bc1s[4*g+0]));
                    a = fma2(XS[p], splat(wcss[4*g+0]), a);
                    z0 = exp2_2(a) + one;
                }
                {
                    v2f a = fma2(XR[p], splat(wcrs[4*g+1]), splat(bc1s[4*g+1]));
                    a = fma2(XS[p], splat(wcss[4*g+1]), a);
                    z1 = exp2_2(a) + one;
                }
                {
                    v2f a = fma2(XR[p], splat(wcrs[4*g+2]), splat(bc1s[4*g+2]));
                    a = fma2(XS[p], splat(wcss[4*g+2]), a);
                    z2 = exp2_2(a) + one;
                }
                {
                    v2f a = fma2(XR[p], splat(wcrs[4*g+3]), splat(bc1s[4*g+3]));
                    a = fma2(XS[p], splat(wcss[4*g+3]), a);
                    z3 = exp2_2(a) + one;
                }
                // batched reciprocal: 1 rcp pair for 4 divisions
                const v2f p2 = z0 * z1;
                const v2f p3 = p2 * z2;
                const v2f p4 = p3 * z3;
                const v2f q  = rcp2(p4);
                const v2f r3 = q  * p3;   // 1/z3
                const v2f q3 = q  * z3;   // 1/(z0 z1 z2)
                const v2f r2 = q3 * p2;   // 1/z2
                const v2f q2 = q3 * z2;   // 1/(z0 z1)
                const v2f r1 = q2 * z0;   // 1/z1
                const v2f r0 = q2 * z1;   // 1/z0
                C[p] = fma2(r0, splat(m2wc2[4*g+0]), C[p]);
                C[p] = fma2(r1, splat(m2wc2[4*g+1]), C[p]);
                C[p] = fma2(r2, splat(m2wc2[4*g+2]), C[p]);
                C[p] = fma2(r3, splat(m2wc2[4*g+3]), C[p]);
            }
        }

        // intrinsic MLP (agent = lane): same batched-rcp structure
#pragma unroll
        for (int g = 0; g < 2; ++g) {
#pragma unroll
            for (int p = 0; p < 2; ++p) {
                v2f z0, z1, z2, z3;
                z0 = exp2_2(fma2(XV[p], splat(w1s[4*g+0]), splat(b1s[4*g+0]))) + one;
                z1 = exp2_2(fma2(XV[p], splat(w1s[4*g+1]), splat(b1s[4*g+1]))) + one;
                z2 = exp2_2(fma2(XV[p], splat(w1s[4*g+2]), splat(b1s[4*g+2]))) + one;
                z3 = exp2_2(fma2(XV[p], splat(w1s[4*g+3]), splat(b1s[4*g+3]))) + one;
                const v2f p2 = z0 * z1;
                const v2f p3 = p2 * z2;
                const v2f p4 = p3 * z3;
                const v2f q  = rcp2(p4);
                const v2f r3 = q  * p3;
                const v2f q3 = q  * z3;
                const v2f r2 = q3 * p2;
                const v2f q2 = q3 * z2;
                const v2f r1 = q2 * z0;
                const v2f r0 = q2 * z1;
                A[p] = fma2(r0, splat(m2w2[4*g+0]), A[p]);
                A[p] = fma2(r1, splat(m2w2[4*g+1]), A[p]);
                A[p] = fma2(r2, splat(m2w2[4*g+2]), A[p]);
                A[p] = fma2(r3, splat(m2w2[4*g+3]), A[p]);
            }
        }

        // symmetric scatter: +contrib at receiver, -contrib at sender
        const float cv[ROWS] = {C[0].x, C[0].y, C[1].x, C[1].y};
        const float av[ROWS] = {A[0].x, A[0].y, A[1].x, A[1].y};
#pragma unroll
        for (int k = 0; k < ROWS; ++k) {
            const float cr = __shfl(cv[k], inv_r, 64);
            const float cs = send_is_id ? cv[k] : __shfl(cv[k], inv_s, 64);
            const int row = row0 + k;
            if (row < B)
                out[(size_t)row * N_AGENTS + lane] = av[k] + cr - cs;
        }
    }
}

extern "C" void kernel_launch(void* const* d_in, const int* in_sizes, int n_in,
                              void* d_out, int out_size, void* d_ws, size_t ws_size,
                              hipStream_t stream) {
    const float* x   = (const float*)d_in[0];
    const float* W1  = (const float*)d_in[1];
    const float* b1  = (const float*)d_in[2];
    const float* W2  = (const float*)d_in[3];
    const float* b2  = (const float*)d_in[4];
    const float* Wc1 = (const float*)d_in[5];
    const float* bc1 = (const float*)d_in[6];
    const float* Wc2 = (const float*)d_in[7];
    const float* bc2 = (const float*)d_in[8];
    const int* send_idx = (const int*)d_in[9];
    const int* recv_idx = (const int*)d_in[10];

    const int B = in_sizes[0] / N_AGENTS;   // 131072

    // 2048 blocks x 4 waves = 8192 waves; 4 rows/iter -> 4 iters per wave
    const int blocks = 2048;
    networked_ode_kernel<<<blocks, dim3(256), 0, stream>>>(
        x, W1, b1, W2, b2, Wc1, bc1, Wc2, bc2, send_idx, recv_idx,
        (float*)d_out, B);
}